// Round 7
// baseline (254.712 us; speedup 1.0000x reference)
//
#include <hip/hip_runtime.h>
#include <hip/hip_bf16.h>
#include <math.h>

// B=8, T=2048, C=1024, H=64 causal single-head attention, scale 1/32.
// wt2 (W -> B-frag order, zeroes tail counters) -> qkv (direct-load MFMA,
// fragment-packed Qf/Kf/Vf outputs) -> attn_part (split-K flash + atomic-tail
// combine). 3 dispatches.

#define BT 16384
#define TSEQ 2048
#define XST 72   // LDS row stride (ushorts)

typedef __attribute__((ext_vector_type(8))) __bf16 bf16x8;
typedef __attribute__((ext_vector_type(8))) unsigned short ushort8;
typedef __attribute__((ext_vector_type(4))) float floatx4;

#define MFMA16(a, b, c) __builtin_amdgcn_mfma_f32_16x16x32_bf16( \
    __builtin_bit_cast(bf16x8, (a)), __builtin_bit_cast(bf16x8, (b)), (c), 0, 0, 0)

__device__ inline unsigned short f2bf(float f) {
  unsigned u = __builtin_bit_cast(unsigned, f);
  u += 0x7FFFu + ((u >> 16) & 1u);   // RNE
  return (unsigned short)(u >> 16);
}
__device__ inline float bf2f(unsigned short s) {
  return __builtin_bit_cast(float, (unsigned)s << 16);
}
__device__ inline ushort8 pack8(floatx4 a, floatx4 b) {
  ushort8 t;
  t[0] = f2bf(a[0]); t[1] = f2bf(a[1]); t[2] = f2bf(a[2]); t[3] = f2bf(a[3]);
  t[4] = f2bf(b[0]); t[5] = f2bf(b[1]); t[6] = f2bf(b[2]); t[7] = f2bf(b[3]);
  return t;
}

// ---------------------------------------------------------------------------
// Kernel 0: Wt2 in MFMA B-fragment order (verified r6) + zero tail counters.
// ---------------------------------------------------------------------------
__global__ __launch_bounds__(256) void wt2_kernel(
    const float* __restrict__ Wq, const float* __restrict__ Wk,
    const float* __restrict__ Wv, unsigned short* __restrict__ Wt2,
    int* __restrict__ cnt) {
  if (blockIdx.x == 0) cnt[threadIdx.x] = 0;   // 256 counters (8 b x 32 qt)
  __shared__ float ls[64][65];
  const int m = blockIdx.x >> 4;
  const int kci = blockIdx.x & 15;
  const int c0 = kci << 6;
  const float* __restrict__ W = (m == 0) ? Wq : (m == 1) ? Wk : Wv;
  const int tid = threadIdx.x;
#pragma unroll
  for (int i = 0; i < 16; ++i) {
    int idx = tid + (i << 8);
    int cl = idx >> 6, h = idx & 63;
    ls[cl][h] = W[(c0 + cl) * 64 + h];
  }
  __syncthreads();
  const int w = tid >> 6, lane = tid & 63;
  const int quad = lane >> 4, l16 = lane & 15;
  const int nt = (m << 2) + w;
#pragma unroll
  for (int half = 0; half < 2; ++half) {
    ushort8 t;
#pragma unroll
    for (int j = 0; j < 8; ++j)
      t[j] = f2bf(ls[(half << 5) + (quad << 3) + j][(w << 4) + l16]);
    *(ushort8*)(Wt2 + ((size_t)(((nt << 4) + kci) * 2 + half) << 9) +
                (lane << 3)) = t;
  }
}

// ---------------------------------------------------------------------------
// Kernel 1: 16-row M-tile, kc split 4 ways across waves (grid 1024 x 256).
// A-frags loaded DIRECTLY from row-major f32 x (lane reads its own row; no
// LDS staging, no lgkm in the loop, 16 independent loads hoistable).
// B-frags coalesced from Wt2. Epilogue: 2-stage LDS reduce (red), then emit
// Qf/Kf/Vf fragment-packed (staging reuses red[1]).
// ---------------------------------------------------------------------------
__global__ __launch_bounds__(256) void qkv_mfma(
    const float* __restrict__ x, const unsigned short* __restrict__ Wt2,
    unsigned short* __restrict__ Qf, unsigned short* __restrict__ Kf,
    unsigned short* __restrict__ Vf) {
  __shared__ float red[2][12][64][4];   // 24.6 KB; red[1] reused as epi staging

  const int tid = threadIdx.x;
  const int w = tid >> 6, lane = tid & 63;
  const int quad = lane >> 4, l16 = lane & 15;
  const int r0 = blockIdx.x << 4;
  const float* __restrict__ xr =
      x + (size_t)(r0 + l16) * 1024 + (w << 8) + (quad << 3);

  floatx4 acc[12];
#pragma unroll
  for (int i = 0; i < 12; ++i) acc[i] = (floatx4){0.f, 0.f, 0.f, 0.f};

#pragma unroll
  for (int it = 0; it < 4; ++it) {
    floatx4 f0 = *(const floatx4*)(xr + (it << 6));
    floatx4 f1 = *(const floatx4*)(xr + (it << 6) + 4);
    floatx4 f2 = *(const floatx4*)(xr + (it << 6) + 32);
    floatx4 f3 = *(const floatx4*)(xr + (it << 6) + 36);
    ushort8 a0 = pack8(f0, f1);
    ushort8 a1 = pack8(f2, f3);
    const unsigned short* bbase =
        Wt2 + ((size_t)((w << 2) + it) << 10) + ((size_t)lane << 3);
#pragma unroll
    for (int nt = 0; nt < 12; ++nt) {
      const unsigned short* bp = bbase + ((size_t)nt << 14);
      ushort8 b0 = *(const ushort8*)bp;
      ushort8 b1 = *(const ushort8*)(bp + 512);
      acc[nt] = MFMA16(a0, b0, acc[nt]);
      acc[nt] = MFMA16(a1, b1, acc[nt]);
    }
  }

  // ---- 2-stage kc reduce (verified r6) ----
  if (w == 1) {
#pragma unroll
    for (int nt = 0; nt < 12; ++nt) *(floatx4*)&red[0][nt][lane][0] = acc[nt];
  } else if (w == 3) {
#pragma unroll
    for (int nt = 0; nt < 12; ++nt) *(floatx4*)&red[1][nt][lane][0] = acc[nt];
  }
  __syncthreads();
  if (w == 0) {
#pragma unroll
    for (int nt = 0; nt < 12; ++nt) acc[nt] += *(const floatx4*)&red[0][nt][lane][0];
  } else if (w == 2) {
#pragma unroll
    for (int nt = 0; nt < 12; ++nt) acc[nt] += *(const floatx4*)&red[1][nt][lane][0];
  }
  __syncthreads();
  if (w == 2) {
#pragma unroll
    for (int nt = 0; nt < 12; ++nt) *(floatx4*)&red[0][nt][lane][0] = acc[nt];
  }
  __syncthreads();
  // ---- wave 0: final sum, then stage q/k row-major + v transposed ----
  unsigned short* su = (unsigned short*)&red[1][0][0][0];  // 7.7 KB used
  unsigned short* qs = su;                    // [16][72]
  unsigned short* ks = su + 16 * XST;         // [16][72]
  unsigned short* vt = su + 32 * XST;         // [64][24]
  if (w == 0) {
#pragma unroll
    for (int nt = 0; nt < 12; ++nt) acc[nt] += *(const floatx4*)&red[0][nt][lane][0];
#pragma unroll
    for (int nt = 0; nt < 4; ++nt)
#pragma unroll
      for (int r = 0; r < 4; ++r)
        qs[((quad << 2) + r) * XST + (nt << 4) + l16] = f2bf(acc[nt][r]);
#pragma unroll
    for (int nt = 4; nt < 8; ++nt)
#pragma unroll
      for (int r = 0; r < 4; ++r)
        ks[((quad << 2) + r) * XST + ((nt - 4) << 4) + l16] = f2bf(acc[nt][r]);
#pragma unroll
    for (int nt = 8; nt < 12; ++nt)
#pragma unroll
      for (int r = 0; r < 4; ++r)
        vt[(((nt - 8) << 4) + l16) * 24 + (quad << 2) + r] = f2bf(acc[nt][r]);
  }
  __syncthreads();

  // ---- emit fragment-packed Qf/Kf/Vf (verified r6) ----
  const int b = r0 >> 11;
  const int r16 = (r0 & 2047) >> 4;
  const int st = (r0 & 2047) >> 6;
  const int ntK = (r0 >> 4) & 3;
  const int khV = (r0 >> 5) & 1;
  const int q0v = (r0 >> 3) & 3;   // 0 or 2
  if (w == 0) {
#pragma unroll
    for (int kh = 0; kh < 2; ++kh) {
      ushort8 t = *(const ushort8*)&qs[l16 * XST + (kh << 5) + (quad << 3)];
      *(ushort8*)(Qf + ((((size_t)b * 128 + r16) * 2 + kh) << 9) + (lane << 3)) = t;
    }
  } else if (w == 1) {
#pragma unroll
    for (int kh = 0; kh < 2; ++kh) {
      ushort8 t = *(const ushort8*)&ks[l16 * XST + (kh << 5) + (quad << 3)];
      *(ushort8*)(Kf + ((((size_t)(b * 32 + st) * 4 + ntK) * 2 + kh) << 9) +
                  (lane << 3)) = t;
    }
  } else {
    if ((quad >> 1) == (q0v >> 1)) {
#pragma unroll
      for (int sub = 0; sub < 2; ++sub) {
        const int ntE = ((w - 2) << 1) + sub;
        ushort8 t = *(const ushort8*)&vt[((ntE << 4) + l16) * 24 +
                                         ((quad - q0v) << 3)];
        *(ushort8*)(Vf + ((((size_t)(b * 32 + st) * 4 + ntE) * 2 + khV) << 9) +
                    (lane << 3)) = t;
      }
    }
  }
}

// ---------------------------------------------------------------------------
// Kernel 2: split-K flash attention with ATOMIC-TAIL combine.
// Block = 4 waves x 16 Q-rows (64-row q-tile), chunk = 4 K-tiles,
// grid = 8 x 144 = 1152. nch==1 (qt<4): write out directly. Else write
// partial slot, fence, atomicAdd; last block per (b,qt) combines -> out.
// ---------------------------------------------------------------------------
__global__ __launch_bounds__(256) void attn_part(
    const unsigned short* __restrict__ Qf, const unsigned short* __restrict__ Kf,
    const unsigned short* __restrict__ Vf, float* __restrict__ part,
    int* __restrict__ cnt, float* __restrict__ out) {
  __shared__ unsigned short Pw[4][16 * XST];
  __shared__ int flag;

  const int tid = threadIdx.x;
  const int w = tid >> 6, lane = tid & 63;
  const int quad = lane >> 4, l16 = lane & 15;
  const int b = blockIdx.x / 144;
  const int e = blockIdx.x - b * 144;
  int g = 0;
#pragma unroll
  for (int gg = 1; gg < 8; ++gg) g += (e >= 2 * gg * (gg + 1)) ? 1 : 0;
  const int rem = e - 2 * g * (g + 1);
  const int qt = (g << 2) + rem / (g + 1);
  const int ch = rem - (rem / (g + 1)) * (g + 1);
  const int s0 = ch << 2;
  const int s1 = min(s0 + 4, qt + 1);
  const int r16 = (qt << 2) + w;

  const unsigned short* qbase =
      Qf + ((((size_t)b * 128 + r16) * 2) << 9) + (lane << 3);
  ushort8 qf0 = *(const ushort8*)qbase;
  ushort8 qf1 = *(const ushort8*)(qbase + 512);

  floatx4 acc[4], lacc;
#pragma unroll
  for (int nt = 0; nt < 4; ++nt) acc[nt] = (floatx4){0.f, 0.f, 0.f, 0.f};
  lacc = (floatx4){0.f, 0.f, 0.f, 0.f};
  const ushort8 ones = {0x3F80, 0x3F80, 0x3F80, 0x3F80,
                        0x3F80, 0x3F80, 0x3F80, 0x3F80};

#define KVIDX(ss, nt, kh) \
  (((((size_t)(b * 32 + (ss)) << 2) + (nt)) * 2 + (kh)) << 9)

  ushort8 bk[4][2];
#pragma unroll
  for (int nt = 0; nt < 4; ++nt)
#pragma unroll
    for (int kh = 0; kh < 2; ++kh)
      bk[nt][kh] = *(const ushort8*)(Kf + KVIDX(s0, nt, kh) + (lane << 3));

  for (int s = s0; s < s1; ++s) {
    const int sn = (s + 1 < s1) ? s + 1 : s;
    ushort8 bv[4][2];
#pragma unroll
    for (int nt = 0; nt < 4; ++nt)
#pragma unroll
      for (int kh = 0; kh < 2; ++kh)
        bv[nt][kh] = *(const ushort8*)(Vf + KVIDX(s, nt, kh) + (lane << 3));
    ushort8 bkn[4][2];
#pragma unroll
    for (int nt = 0; nt < 4; ++nt)
#pragma unroll
      for (int kh = 0; kh < 2; ++kh)
        bkn[nt][kh] = *(const ushort8*)(Kf + KVIDX(sn, nt, kh) + (lane << 3));

    // S = Q K^T
    floatx4 sf[4];
#pragma unroll
    for (int nt = 0; nt < 4; ++nt) {
      sf[nt] = (floatx4){0.f, 0.f, 0.f, 0.f};
      sf[nt] = MFMA16(qf0, bk[nt][0], sf[nt]);
      sf[nt] = MFMA16(qf1, bk[nt][1], sf[nt]);
    }

    // P = exp2(S * log2e/32)  (no max-shift; masked -> 0)
    const bool diag = (s == qt);
    const int qrow = (w << 4) + (quad << 2);
#pragma unroll
    for (int nt = 0; nt < 4; ++nt) {
      const int keyl = (nt << 4) + l16;
#pragma unroll
      for (int r = 0; r < 4; ++r) {
        float ev = exp2f(sf[nt][r] * 0.04508422f);
        if (diag && keyl > qrow + r) ev = 0.f;
        Pw[w][((quad << 2) + r) * XST + keyl] = f2bf(ev);
      }
    }

    // O += P V ; l += P 1   (same-wave LDS round trip)
#pragma unroll
    for (int kh = 0; kh < 2; ++kh) {
      ushort8 pa = *(const ushort8*)&Pw[w][l16 * XST + (kh << 5) + (quad << 3)];
      lacc = MFMA16(pa, ones, lacc);
#pragma unroll
      for (int nt = 0; nt < 4; ++nt) acc[nt] = MFMA16(pa, bv[nt][kh], acc[nt]);
    }
#pragma unroll
    for (int nt = 0; nt < 4; ++nt) {
      bk[nt][0] = bkn[nt][0];
      bk[nt][1] = bkn[nt][1];
    }
  }
#undef KVIDX

  const int nch = g + 1;
  if (nch == 1) {
    // single-chunk q-tile: write out directly (block-uniform path)
#pragma unroll
    for (int r = 0; r < 4; ++r) {
      const float inv = 1.f / lacc[r];
      const size_t orow =
          (size_t)b * TSEQ + (qt << 6) + (w << 4) + (quad << 2) + r;
#pragma unroll
      for (int nt = 0; nt < 4; ++nt)
        out[orow * 64 + (nt << 4) + l16] = acc[nt][r] * inv;
    }
    return;
  }

  // write partial slot: l[64] f32 + o[64][64] bf16
  float* slot = part + (size_t)(b * 144 + e) * 2112;
  if (l16 == 0) {
#pragma unroll
    for (int r = 0; r < 4; ++r) slot[(w << 4) + (quad << 2) + r] = lacc[r];
  }
  unsigned short* op = (unsigned short*)(slot + 64);
#pragma unroll
  for (int nt = 0; nt < 4; ++nt)
#pragma unroll
    for (int r = 0; r < 4; ++r)
      op[((w << 4) + (quad << 2) + r) * 64 + (nt << 4) + l16] = f2bf(acc[nt][r]);

  __syncthreads();                       // drains this block's stores (vmcnt 0)
  if (tid == 0) {
    __threadfence();                     // device-scope release (L2 writeback)
    flag = (atomicAdd(&cnt[(b << 5) + qt], 1) == nch - 1) ? 1 : 0;
  }
  __syncthreads();
  if (!flag) return;

  __threadfence();                       // device-scope acquire (invalidate)
  const int row = tid >> 2, hseg = (tid & 3) << 4;
  const int ebase = e - ch;
  float l = 0.f;
  float ov[16];
#pragma unroll
  for (int i = 0; i < 16; ++i) ov[i] = 0.f;
  for (int c = 0; c < nch; ++c) {
    const float* sl = part + (size_t)(b * 144 + ebase + c) * 2112;
    l += sl[row];
    const unsigned short* o16 = (const unsigned short*)(sl + 64) + row * 64 + hseg;
    ushort8 o0 = *(const ushort8*)o16;
    ushort8 o1 = *(const ushort8*)(o16 + 8);
#pragma unroll
    for (int i = 0; i < 8; ++i) ov[i] += bf2f(o0[i]);
#pragma unroll
    for (int i = 0; i < 8; ++i) ov[8 + i] += bf2f(o1[i]);
  }
  const float inv = 1.f / l;
  float* o = out + ((size_t)b * TSEQ + (qt << 6) + row) * 64 + hseg;
#pragma unroll
  for (int i = 0; i < 16; ++i) o[i] = ov[i] * inv;
}

extern "C" void kernel_launch(void* const* d_in, const int* in_sizes, int n_in,
                              void* d_out, int out_size, void* d_ws, size_t ws_size,
                              hipStream_t stream) {
  const float* x  = (const float*)d_in[0];
  const float* Wk = (const float*)d_in[1];
  const float* Wq = (const float*)d_in[2];
  const float* Wv = (const float*)d_in[3];

  unsigned short* Qfw = (unsigned short*)d_ws;          // 2 MB
  unsigned short* Kfw = Qfw + (size_t)BT * 64;          // 2 MB
  unsigned short* Vfw = Kfw + (size_t)BT * 64;          // 2 MB
  unsigned short* Wt2 = Vfw + (size_t)BT * 64;          // 384 KB
  float* part = (float*)(Wt2 + 3 * 64 * 1024);          // 1152*8448 B = 9.7 MB
  int* cnt = (int*)(part + (size_t)1152 * 2112);        // 1 KB

  wt2_kernel<<<48, 256, 0, stream>>>(Wq, Wk, Wv, Wt2, cnt);
  qkv_mfma<<<1024, 256, 0, stream>>>(x, Wt2, Qfw, Kfw, Vfw);
  attn_part<<<1152, 256, 0, stream>>>(Qfw, Kfw, Vfw, part, cnt, (float*)d_out);
}

// Round 8
// 145.864 us; speedup vs baseline: 1.7462x; 1.7462x over previous
//
#include <hip/hip_runtime.h>
#include <hip/hip_bf16.h>
#include <math.h>

// B=8, T=2048, C=1024, H=64 causal single-head attention, scale 1/32.
// wt2 (W -> B-frag order) -> qkv (16-row x kc/4 blocks, fragment-packed
// Qf/Kf/Vf outputs) -> attn_part (split-K flash, 32 Q-rows/wave sharing K/V
// frags) -> attn_combine.  [R7 atomic-tail reverted: device-scope fences
// serialized 1152 blocks; separate combine dispatch is cheaper.]

#define BT 16384
#define TSEQ 2048
#define XST 72   // LDS row stride (ushorts)

typedef __attribute__((ext_vector_type(8))) __bf16 bf16x8;
typedef __attribute__((ext_vector_type(8))) unsigned short ushort8;
typedef __attribute__((ext_vector_type(4))) float floatx4;

#define MFMA16(a, b, c) __builtin_amdgcn_mfma_f32_16x16x32_bf16( \
    __builtin_bit_cast(bf16x8, (a)), __builtin_bit_cast(bf16x8, (b)), (c), 0, 0, 0)

__device__ inline unsigned short f2bf(float f) {
  unsigned u = __builtin_bit_cast(unsigned, f);
  u += 0x7FFFu + ((u >> 16) & 1u);   // RNE
  return (unsigned short)(u >> 16);
}
__device__ inline float bf2f(unsigned short s) {
  return __builtin_bit_cast(float, (unsigned)s << 16);
}
__device__ inline unsigned long long pack4bf(floatx4 f) {
  return (unsigned long long)f2bf(f[0]) | ((unsigned long long)f2bf(f[1]) << 16) |
         ((unsigned long long)f2bf(f[2]) << 32) | ((unsigned long long)f2bf(f[3]) << 48);
}

// ---------------------------------------------------------------------------
// Kernel 0: Wt2 in MFMA B-fragment order (verified r6).
// ---------------------------------------------------------------------------
__global__ __launch_bounds__(256) void wt2_kernel(
    const float* __restrict__ Wq, const float* __restrict__ Wk,
    const float* __restrict__ Wv, unsigned short* __restrict__ Wt2) {
  __shared__ float ls[64][65];
  const int m = blockIdx.x >> 4;
  const int kci = blockIdx.x & 15;
  const int c0 = kci << 6;
  const float* __restrict__ W = (m == 0) ? Wq : (m == 1) ? Wk : Wv;
  const int tid = threadIdx.x;
#pragma unroll
  for (int i = 0; i < 16; ++i) {
    int idx = tid + (i << 8);
    int cl = idx >> 6, h = idx & 63;
    ls[cl][h] = W[(c0 + cl) * 64 + h];
  }
  __syncthreads();
  const int w = tid >> 6, lane = tid & 63;
  const int quad = lane >> 4, l16 = lane & 15;
  const int nt = (m << 2) + w;
#pragma unroll
  for (int half = 0; half < 2; ++half) {
    ushort8 t;
#pragma unroll
    for (int j = 0; j < 8; ++j)
      t[j] = f2bf(ls[(half << 5) + (quad << 3) + j][(w << 4) + l16]);
    *(ushort8*)(Wt2 + ((size_t)(((nt << 4) + kci) * 2 + half) << 9) +
                (lane << 3)) = t;
  }
}

// ---------------------------------------------------------------------------
// Kernel 1: qkv (verbatim r6 — 43 µs proven). 16-row M-tile, kc split 4 ways
// across waves; wave-private LDS dbuf staging; fragment-packed emit.
// ---------------------------------------------------------------------------
__global__ __launch_bounds__(256) void qkv_mfma(
    const float* __restrict__ x, const unsigned short* __restrict__ Wt2,
    unsigned short* __restrict__ Qf, unsigned short* __restrict__ Kf,
    unsigned short* __restrict__ Vf) {
  __shared__ unsigned short region[4][16 * XST];
  __shared__ float red[2][12][64][4];

  const int tid = threadIdx.x;
  const int w = tid >> 6, lane = tid & 63;
  const int quad = lane >> 4, l16 = lane & 15;
  const int r0 = blockIdx.x << 4;
  const float* __restrict__ xw = x + (size_t)r0 * 1024 + (w << 8);
  const int srow = lane >> 4, scol = (lane & 15) << 2;

  floatx4 acc[12];
#pragma unroll
  for (int i = 0; i < 12; ++i) acc[i] = (floatx4){0.f, 0.f, 0.f, 0.f};

  floatx4 pf[2][4];
#pragma unroll
  for (int i = 0; i < 4; ++i)
    pf[0][i] = *(const floatx4*)(xw + (size_t)((i << 2) + srow) * 1024 + scol);
#pragma unroll
  for (int i = 0; i < 4; ++i)
    pf[1][i] = *(const floatx4*)(xw + (size_t)((i << 2) + srow) * 1024 + 64 + scol);

  unsigned short* buf = &region[w][0];
#pragma unroll
  for (int it = 0; it < 4; ++it) {
#pragma unroll
    for (int i = 0; i < 4; ++i)
      *(unsigned long long*)&buf[((i << 2) + srow) * XST + scol] =
          pack4bf(pf[it & 1][i]);
    if (it < 2) {
#pragma unroll
      for (int i = 0; i < 4; ++i)
        pf[it & 1][i] = *(const floatx4*)(xw + (size_t)((i << 2) + srow) * 1024 +
                                          ((it + 2) << 6) + scol);
    }
    ushort8 a0 = *(const ushort8*)&buf[l16 * XST + (quad << 3)];
    ushort8 a1 = *(const ushort8*)&buf[l16 * XST + 32 + (quad << 3)];
    const int kci = (w << 2) + it;
    const unsigned short* bbase = Wt2 + ((size_t)kci << 10) + ((size_t)lane << 3);
#pragma unroll
    for (int nt = 0; nt < 12; ++nt) {
      const unsigned short* bp = bbase + ((size_t)nt << 14);
      ushort8 b0 = *(const ushort8*)bp;
      ushort8 b1 = *(const ushort8*)(bp + 512);
      acc[nt] = MFMA16(a0, b0, acc[nt]);
      acc[nt] = MFMA16(a1, b1, acc[nt]);
    }
  }

  if (w == 1) {
#pragma unroll
    for (int nt = 0; nt < 12; ++nt) *(floatx4*)&red[0][nt][lane][0] = acc[nt];
  } else if (w == 3) {
#pragma unroll
    for (int nt = 0; nt < 12; ++nt) *(floatx4*)&red[1][nt][lane][0] = acc[nt];
  }
  __syncthreads();
  if (w == 0) {
#pragma unroll
    for (int nt = 0; nt < 12; ++nt) acc[nt] += *(const floatx4*)&red[0][nt][lane][0];
  } else if (w == 2) {
#pragma unroll
    for (int nt = 0; nt < 12; ++nt) acc[nt] += *(const floatx4*)&red[1][nt][lane][0];
  }
  __syncthreads();
  if (w == 2) {
#pragma unroll
    for (int nt = 0; nt < 12; ++nt) *(floatx4*)&red[0][nt][lane][0] = acc[nt];
  }
  __syncthreads();
  unsigned short* qs = &region[0][0];          // [16][72]
  unsigned short* ks = qs + 16 * XST;          // [16][72]
  unsigned short* vt = ks + 16 * XST;          // [64][24]
  if (w == 0) {
#pragma unroll
    for (int nt = 0; nt < 12; ++nt) acc[nt] += *(const floatx4*)&red[0][nt][lane][0];
#pragma unroll
    for (int nt = 0; nt < 4; ++nt)
#pragma unroll
      for (int r = 0; r < 4; ++r)
        qs[((quad << 2) + r) * XST + (nt << 4) + l16] = f2bf(acc[nt][r]);
#pragma unroll
    for (int nt = 4; nt < 8; ++nt)
#pragma unroll
      for (int r = 0; r < 4; ++r)
        ks[((quad << 2) + r) * XST + ((nt - 4) << 4) + l16] = f2bf(acc[nt][r]);
#pragma unroll
    for (int nt = 8; nt < 12; ++nt)
#pragma unroll
      for (int r = 0; r < 4; ++r)
        vt[(((nt - 8) << 4) + l16) * 24 + (quad << 2) + r] = f2bf(acc[nt][r]);
  }
  __syncthreads();

  const int b = r0 >> 11;
  const int r16 = (r0 & 2047) >> 4;
  const int st = (r0 & 2047) >> 6;
  const int ntK = (r0 >> 4) & 3;
  const int khV = (r0 >> 5) & 1;
  const int q0v = (r0 >> 3) & 3;
  if (w == 0) {
#pragma unroll
    for (int kh = 0; kh < 2; ++kh) {
      ushort8 t = *(const ushort8*)&qs[l16 * XST + (kh << 5) + (quad << 3)];
      *(ushort8*)(Qf + ((((size_t)b * 128 + r16) * 2 + kh) << 9) + (lane << 3)) = t;
    }
  } else if (w == 1) {
#pragma unroll
    for (int kh = 0; kh < 2; ++kh) {
      ushort8 t = *(const ushort8*)&ks[l16 * XST + (kh << 5) + (quad << 3)];
      *(ushort8*)(Kf + ((((size_t)(b * 32 + st) * 4 + ntK) * 2 + kh) << 9) +
                  (lane << 3)) = t;
    }
  } else {
    if ((quad >> 1) == (q0v >> 1)) {
#pragma unroll
      for (int sub = 0; sub < 2; ++sub) {
        const int ntE = ((w - 2) << 1) + sub;
        ushort8 t = *(const ushort8*)&vt[((ntE << 4) + l16) * 24 +
                                         ((quad - q0v) << 3)];
        *(ushort8*)(Vf + ((((size_t)(b * 32 + st) * 4 + ntE) * 2 + khV) << 9) +
                    (lane << 3)) = t;
      }
    }
  }
}

// ---------------------------------------------------------------------------
// Kernel 2: split-K flash attention. Wave owns 32 Q-rows (two 16-row A-frag
// halves mh=0,1) SHARING one set of K/V fragment loads -> 36 MFMA per 8
// ushort8 K-loads (2x the MFMA density of r6). Block = 2 waves = 64-row
// q-tile; grid = 8 x 144. exp2f folds the 1/32 scale. No-max softmax.
// ---------------------------------------------------------------------------
__global__ __launch_bounds__(128) void attn_part(
    const unsigned short* __restrict__ Qf, const unsigned short* __restrict__ Kf,
    const unsigned short* __restrict__ Vf, float* __restrict__ part) {
  __shared__ unsigned short Pw[2][32 * XST];   // per wave: rows 0..31

  const int tid = threadIdx.x;
  const int w = tid >> 6, lane = tid & 63;
  const int quad = lane >> 4, l16 = lane & 15;
  const int b = blockIdx.x / 144;
  const int e = blockIdx.x - b * 144;
  int g = 0;
#pragma unroll
  for (int gg = 1; gg < 8; ++gg) g += (e >= 2 * gg * (gg + 1)) ? 1 : 0;
  const int rem = e - 2 * g * (g + 1);
  const int qt = (g << 2) + rem / (g + 1);
  const int ch = rem - (rem / (g + 1)) * (g + 1);
  const int s0 = ch << 2;
  const int s1 = min(s0 + 4, qt + 1);

  // Q A-frags for both 16-row halves: r16 = qt*4 + w*2 + mh
  ushort8 qf[2][2];
#pragma unroll
  for (int mh = 0; mh < 2; ++mh) {
    const unsigned short* qbase =
        Qf + ((((size_t)b * 128 + (qt << 2) + (w << 1) + mh) * 2) << 9) +
        (lane << 3);
    qf[mh][0] = *(const ushort8*)qbase;
    qf[mh][1] = *(const ushort8*)(qbase + 512);
  }

  floatx4 acc[2][4], lacc[2];
#pragma unroll
  for (int mh = 0; mh < 2; ++mh) {
#pragma unroll
    for (int nt = 0; nt < 4; ++nt) acc[mh][nt] = (floatx4){0.f, 0.f, 0.f, 0.f};
    lacc[mh] = (floatx4){0.f, 0.f, 0.f, 0.f};
  }
  const ushort8 ones = {0x3F80, 0x3F80, 0x3F80, 0x3F80,
                        0x3F80, 0x3F80, 0x3F80, 0x3F80};

#define KVIDX(ss, nt, kh) \
  (((((size_t)(b * 32 + (ss)) << 2) + (nt)) * 2 + (kh)) << 9)

  for (int s = s0; s < s1; ++s) {
    // K + V fragments (each a single coalesced 1KB wave-load), shared by both mh
    ushort8 bk[4][2], bv[4][2];
#pragma unroll
    for (int nt = 0; nt < 4; ++nt)
#pragma unroll
      for (int kh = 0; kh < 2; ++kh) {
        bk[nt][kh] = *(const ushort8*)(Kf + KVIDX(s, nt, kh) + (lane << 3));
        bv[nt][kh] = *(const ushort8*)(Vf + KVIDX(s, nt, kh) + (lane << 3));
      }

    // S = Q K^T  (16 MFMA, two independent chains mh=0/1)
    floatx4 sf[2][4];
#pragma unroll
    for (int mh = 0; mh < 2; ++mh)
#pragma unroll
      for (int nt = 0; nt < 4; ++nt) {
        sf[mh][nt] = (floatx4){0.f, 0.f, 0.f, 0.f};
        sf[mh][nt] = MFMA16(qf[mh][0], bk[nt][0], sf[mh][nt]);
        sf[mh][nt] = MFMA16(qf[mh][1], bk[nt][1], sf[mh][nt]);
      }

    // P = exp2(S * log2e/32)  (no max-shift; masked -> 0)
    const bool diag = (s == qt);
#pragma unroll
    for (int mh = 0; mh < 2; ++mh) {
      const int qrow = (w << 5) + (mh << 4) + (quad << 2);
#pragma unroll
      for (int nt = 0; nt < 4; ++nt) {
        const int keyl = (nt << 4) + l16;
#pragma unroll
        for (int r = 0; r < 4; ++r) {
          float ev = exp2f(sf[mh][nt][r] * 0.04508422f);
          if (diag && keyl > qrow + r) ev = 0.f;
          Pw[w][((mh << 4) + (quad << 2) + r) * XST + keyl] = f2bf(ev);
        }
      }
    }

    // O += P V ; l += P 1  (same-wave LDS round trip; 20 MFMA)
#pragma unroll
    for (int kh = 0; kh < 2; ++kh) {
#pragma unroll
      for (int mh = 0; mh < 2; ++mh) {
        ushort8 pa = *(const ushort8*)&Pw[w][((mh << 4) + l16) * XST +
                                             (kh << 5) + (quad << 3)];
        lacc[mh] = MFMA16(pa, ones, lacc[mh]);
#pragma unroll
        for (int nt = 0; nt < 4; ++nt)
          acc[mh][nt] = MFMA16(pa, bv[nt][kh], acc[mh][nt]);
      }
    }
  }
#undef KVIDX

  // partial slot: l[64] f32 + o[64][64] bf16; wave w owns rows w*32..w*32+31.
  float* slot = part + (size_t)(b * 144 + e) * 2112;
  if (l16 == 0) {
#pragma unroll
    for (int mh = 0; mh < 2; ++mh)
#pragma unroll
      for (int r = 0; r < 4; ++r)
        slot[(w << 5) + (mh << 4) + (quad << 2) + r] = lacc[mh][r];
  }
  unsigned short* op = (unsigned short*)(slot + 64);
#pragma unroll
  for (int mh = 0; mh < 2; ++mh)
#pragma unroll
    for (int nt = 0; nt < 4; ++nt)
#pragma unroll
      for (int r = 0; r < 4; ++r)
        op[((w << 5) + (mh << 4) + (quad << 2) + r) * 64 + (nt << 4) + l16] =
            f2bf(acc[mh][nt][r]);
}

// ---------------------------------------------------------------------------
// Kernel 3: combine <=8 partials: out = (sum o_i)/(sum l_i). grid = 512.
// ---------------------------------------------------------------------------
__global__ __launch_bounds__(256) void attn_combine(
    const float* __restrict__ part, float* __restrict__ out) {
  const int rh = blockIdx.x & 1;
  const int bqt = blockIdx.x >> 1;
  const int b = bqt >> 5, qt = bqt & 31;
  const int tid = threadIdx.x;
  const int row = (rh << 5) + (tid >> 3);
  const int hseg = (tid & 7) << 3;
  const int g = qt >> 2;
  const int nch = g + 1;
  const int ebase = 2 * g * (g + 1) + (qt & 3) * (g + 1);

  float l = 0.f;
  float ov[8];
#pragma unroll
  for (int i = 0; i < 8; ++i) ov[i] = 0.f;
  for (int c = 0; c < nch; ++c) {
    const float* slot = part + (size_t)(b * 144 + ebase + c) * 2112;
    l += slot[row];
    ushort8 o0 = *(const ushort8*)((const unsigned short*)(slot + 64) +
                                   row * 64 + hseg);
#pragma unroll
    for (int i = 0; i < 8; ++i) ov[i] += bf2f(o0[i]);
  }
  const float inv = 1.f / l;
  float* o = out + ((size_t)(b * TSEQ + (qt << 6) + row)) * 64 + hseg;
#pragma unroll
  for (int i = 0; i < 8; ++i) o[i] = ov[i] * inv;
}

extern "C" void kernel_launch(void* const* d_in, const int* in_sizes, int n_in,
                              void* d_out, int out_size, void* d_ws, size_t ws_size,
                              hipStream_t stream) {
  const float* x  = (const float*)d_in[0];
  const float* Wk = (const float*)d_in[1];
  const float* Wq = (const float*)d_in[2];
  const float* Wv = (const float*)d_in[3];

  unsigned short* Qfw = (unsigned short*)d_ws;          // 2 MB
  unsigned short* Kfw = Qfw + (size_t)BT * 64;          // 2 MB
  unsigned short* Vfw = Kfw + (size_t)BT * 64;          // 2 MB
  unsigned short* Wt2 = Vfw + (size_t)BT * 64;          // 384 KB
  float* part = (float*)(Wt2 + 3 * 64 * 1024);          // 1152*8448 B = 9.7 MB

  wt2_kernel<<<48, 256, 0, stream>>>(Wq, Wk, Wv, Wt2);
  qkv_mfma<<<1024, 256, 0, stream>>>(x, Wt2, Qfw, Kfw, Vfw);
  attn_part<<<1152, 128, 0, stream>>>(Qfw, Kfw, Vfw, part);
  attn_combine<<<512, 256, 0, stream>>>(part, (float*)d_out);
}